// Round 1
// baseline (921.074 us; speedup 1.0000x reference)
//
#include <hip/hip_runtime.h>

// ---------------------------------------------------------------------------
// EdgeNet: 2-layer GCN encode + dot-product edge decode, all fp32.
// Pipeline: deg count -> dinv -> scan(CSR rowptr) -> fill CSR ->
//           GEMM1 -> agg+bias+relu -> GEMM2 -> agg+bias -> edge dot decode.
// ---------------------------------------------------------------------------

__global__ __launch_bounds__(256) void count_deg_k(const int* __restrict__ dst, int E,
                                                   int* __restrict__ deg) {
  int i = blockIdx.x * 256 + threadIdx.x;
  if (i < E) atomicAdd(&deg[dst[i]], 1);
}

__global__ __launch_bounds__(256) void dinv_k(const int* __restrict__ deg,
                                              float* __restrict__ dinv, int n) {
  int i = blockIdx.x * 256 + threadIdx.x;
  if (i < n) dinv[i] = rsqrtf((float)(deg[i] + 1));  // +1 self-loop; deg>=1 always
}

// Single-block exclusive scan of per-node counts -> rowptr (and cursor copy).
__global__ __launch_bounds__(1024) void scan_k(const int* __restrict__ cnt, int n,
                                               int* __restrict__ rowptr,
                                               int* __restrict__ cursor) {
  __shared__ int sums[1024];
  const int tid = threadIdx.x;
  const int chunk = (n + 1023) / 1024;
  const int start = tid * chunk;
  const int end = min(start + chunk, n);
  int s = 0;
  for (int i = start; i < end; ++i) s += cnt[i];
  sums[tid] = s;
  __syncthreads();
  for (int off = 1; off < 1024; off <<= 1) {
    int t = (tid >= off) ? sums[tid - off] : 0;
    __syncthreads();
    sums[tid] += t;
    __syncthreads();
  }
  int run = sums[tid] - s;  // exclusive prefix of this thread's chunk
  for (int i = start; i < end; ++i) {
    rowptr[i] = run;
    cursor[i] = run;
    run += cnt[i];
  }
  if (tid == 1023) rowptr[n] = run;  // == E
}

__global__ __launch_bounds__(256) void fill_csr_k(const int* __restrict__ src,
                                                  const int* __restrict__ dst, int E,
                                                  int* __restrict__ cursor,
                                                  int* __restrict__ csr_src) {
  int i = blockIdx.x * 256 + threadIdx.x;
  if (i < E) {
    int d = dst[i];
    int pos = atomicAdd(&cursor[d], 1);
    csr_src[pos] = src[i];
  }
}

// ---------------------------------------------------------------------------
// fp32 tiled GEMM: C[M,N] = A[M,K] @ B[K,N].  Block = (BM/TM)*(BN/TN) = 256.
// ---------------------------------------------------------------------------
template <int BM, int BN, int BK, int TM, int TN>
__global__ __launch_bounds__(256) void gemm_tiled(const float* __restrict__ A,
                                                  const float* __restrict__ B,
                                                  float* __restrict__ C, int M, int K,
                                                  int N) {
  __shared__ float As[BK][BM];  // transposed A tile
  __shared__ float Bs[BK][BN];
  const int tid = threadIdx.x;
  const int tx = tid % (BN / TN);
  const int ty = tid / (BN / TN);
  const int rowBase = blockIdx.x * BM;
  const int colBase = blockIdx.y * BN;

  float acc[TM][TN];
#pragma unroll
  for (int i = 0; i < TM; ++i)
#pragma unroll
    for (int j = 0; j < TN; ++j) acc[i][j] = 0.f;

  for (int k0 = 0; k0 < K; k0 += BK) {
    // A tile: BM x BK, one float4 per thread along K (BM*BK/4 == 256)
    {
      const int arow = tid / (BK / 4);
      const int acol4 = (tid % (BK / 4)) * 4;
      const int gr = rowBase + arow;
      float4 v;
      if (gr < M)
        v = *reinterpret_cast<const float4*>(&A[(size_t)gr * K + k0 + acol4]);
      else
        v = make_float4(0.f, 0.f, 0.f, 0.f);
      As[acol4 + 0][arow] = v.x;
      As[acol4 + 1][arow] = v.y;
      As[acol4 + 2][arow] = v.z;
      As[acol4 + 3][arow] = v.w;
    }
    // B tile: BK x BN
    for (int i = tid; i < BK * BN / 4; i += 256) {
      const int brow = i / (BN / 4);
      const int bcol4 = (i % (BN / 4)) * 4;
      float4 v = *reinterpret_cast<const float4*>(
          &B[(size_t)(k0 + brow) * N + colBase + bcol4]);
      *reinterpret_cast<float4*>(&Bs[brow][bcol4]) = v;
    }
    __syncthreads();
#pragma unroll
    for (int kk = 0; kk < BK; ++kk) {
      float ra[TM], rb[TN];
#pragma unroll
      for (int i = 0; i < TM; ++i) ra[i] = As[kk][ty * TM + i];
#pragma unroll
      for (int j = 0; j < TN; ++j) rb[j] = Bs[kk][tx * TN + j];
#pragma unroll
      for (int i = 0; i < TM; ++i)
#pragma unroll
        for (int j = 0; j < TN; ++j) acc[i][j] += ra[i] * rb[j];
    }
    __syncthreads();
  }
#pragma unroll
  for (int i = 0; i < TM; ++i) {
    const int gr = rowBase + ty * TM + i;
    if (gr < M) {
#pragma unroll
      for (int j = 0; j < TN; j += 4) {
        float4 v = {acc[i][j], acc[i][j + 1], acc[i][j + 2], acc[i][j + 3]};
        *reinterpret_cast<float4*>(&C[(size_t)gr * N + colBase + tx * TN + j]) = v;
      }
    }
  }
}

// ---------------------------------------------------------------------------
// Wave-per-node normalized aggregation (+ self loop, + bias, optional ReLU).
// C == feature width (128: float2/lane, 64: float/lane).
// ---------------------------------------------------------------------------
template <int C, bool RELU>
__global__ __launch_bounds__(256) void agg_k(const float* __restrict__ hin,
                                             const int* __restrict__ rowptr,
                                             const int* __restrict__ csr_src,
                                             const float* __restrict__ dinv,
                                             const float* __restrict__ bias,
                                             float* __restrict__ hout, int n) {
  const int wid = (blockIdx.x * blockDim.x + threadIdx.x) >> 6;
  const int lane = threadIdx.x & 63;
  if (wid >= n) return;
  const float dd = dinv[wid];
  const int beg = rowptr[wid];
  const int end = rowptr[wid + 1];
  if (C == 128) {
    float2 acc = {0.f, 0.f};
    for (int e = beg; e < end; ++e) {
      const int s = csr_src[e];
      const float w = dinv[s] * dd;
      const float2 v = *reinterpret_cast<const float2*>(&hin[(size_t)s * 128 + lane * 2]);
      acc.x += v.x * w;
      acc.y += v.y * w;
    }
    {  // self loop
      const float w = dd * dd;
      const float2 v =
          *reinterpret_cast<const float2*>(&hin[(size_t)wid * 128 + lane * 2]);
      acc.x += v.x * w;
      acc.y += v.y * w;
    }
    const float2 b = *reinterpret_cast<const float2*>(&bias[lane * 2]);
    acc.x += b.x;
    acc.y += b.y;
    if (RELU) {
      acc.x = fmaxf(acc.x, 0.f);
      acc.y = fmaxf(acc.y, 0.f);
    }
    *reinterpret_cast<float2*>(&hout[(size_t)wid * 128 + lane * 2]) = acc;
  } else {  // C == 64
    float acc = 0.f;
    for (int e = beg; e < end; ++e) {
      const int s = csr_src[e];
      acc += hin[(size_t)s * 64 + lane] * (dinv[s] * dd);
    }
    acc += hin[(size_t)wid * 64 + lane] * (dd * dd);
    acc += bias[lane];
    hout[(size_t)wid * 64 + lane] = acc;
  }
}

// ---------------------------------------------------------------------------
// Decode: 16 lanes per edge, float4 chunks of z[.,64], shuffle reduce.
// ---------------------------------------------------------------------------
__global__ __launch_bounds__(256) void decode_k(const int* __restrict__ pos,
                                                const int* __restrict__ neg,
                                                const float* __restrict__ z,
                                                float* __restrict__ out, int EP) {
  const long long t = (long long)blockIdx.x * 256 + threadIdx.x;
  const long long e = t >> 4;
  const int lane = (int)(t & 15);
  if (e >= 2LL * EP) return;
  int u, v;
  if (e < EP) {
    u = pos[e];
    v = pos[EP + e];
  } else {
    u = neg[e - EP];
    v = neg[EP + (e - EP)];
  }
  const float4 a = *reinterpret_cast<const float4*>(&z[(size_t)u * 64 + lane * 4]);
  const float4 b = *reinterpret_cast<const float4*>(&z[(size_t)v * 64 + lane * 4]);
  float p = a.x * b.x + a.y * b.y + a.z * b.z + a.w * b.w;
#pragma unroll
  for (int off = 8; off > 0; off >>= 1) p += __shfl_down(p, off, 16);
  if (lane == 0) out[e] = p;
}

// ---------------------------------------------------------------------------

extern "C" void kernel_launch(void* const* d_in, const int* in_sizes, int n_in,
                              void* d_out, int out_size, void* d_ws, size_t ws_size,
                              hipStream_t stream) {
  const float* x = (const float*)d_in[0];
  const int* ei = (const int*)d_in[1];
  const int* pos = (const int*)d_in[2];
  const int* neg = (const int*)d_in[3];
  const float* W1 = (const float*)d_in[4];
  const float* b1 = (const float*)d_in[5];
  const float* W2 = (const float*)d_in[6];
  const float* b2 = (const float*)d_in[7];
  float* out = (float*)d_out;

  const int H = in_sizes[5];        // 128
  const int IN = in_sizes[4] / H;   // 256
  const int OUT = in_sizes[7];      // 64
  const int N = in_sizes[0] / IN;   // 100000
  const int E = in_sizes[1] / 2;    // 1600000
  const int EP = in_sizes[2] / 2;   // 500000

  char* ws = (char*)d_ws;
  size_t off = 0;
  auto carve = [&](size_t bytes) -> char* {
    char* p = ws + off;
    off += (bytes + 255) & ~(size_t)255;
    return p;
  };
  int* degi = (int*)carve((size_t)N * 4);
  float* dinvb = (float*)carve((size_t)N * 4);
  int* rowptr = (int*)carve((size_t)(N + 1) * 4);
  int* cursor = (int*)carve((size_t)N * 4);
  int* csr = (int*)carve((size_t)E * 4);
  float* bufA = (float*)carve((size_t)N * H * 4);  // h0, then h1
  float* bufB = (float*)carve((size_t)N * H * 4);  // h, then z
  (void)ws_size;

  const int* srcp = ei;
  const int* dstp = ei + E;

  hipMemsetAsync(degi, 0, (size_t)N * 4, stream);
  count_deg_k<<<(E + 255) / 256, 256, 0, stream>>>(dstp, E, degi);
  dinv_k<<<(N + 255) / 256, 256, 0, stream>>>(degi, dinvb, N);
  scan_k<<<1, 1024, 0, stream>>>(degi, N, rowptr, cursor);
  fill_csr_k<<<(E + 255) / 256, 256, 0, stream>>>(srcp, dstp, E, cursor, csr);

  // GEMM1: h0 = x @ W1   [N,256]@[256,128]
  gemm_tiled<64, 128, 16, 4, 8>
      <<<dim3((N + 63) / 64, 1), 256, 0, stream>>>(x, W1, bufA, N, IN, H);
  // agg1: h = relu(scatter(h0*norm) + b1)
  agg_k<128, true><<<(N + 3) / 4, 256, 0, stream>>>(bufA, rowptr, csr, dinvb, b1,
                                                    bufB, N);
  // GEMM2: h1 = h @ W2   [N,128]@[128,64]
  gemm_tiled<64, 64, 16, 4, 4>
      <<<dim3((N + 63) / 64, 1), 256, 0, stream>>>(bufB, W2, bufA, N, H, OUT);
  // agg2: z = scatter(h1*norm) + b2
  agg_k<64, false><<<(N + 3) / 4, 256, 0, stream>>>(bufA, rowptr, csr, dinvb, b2,
                                                    bufB, N);
  // decode: out[e] = <z_u, z_v>
  const long long threads = 2LL * EP * 16;
  decode_k<<<(int)((threads + 255) / 256), 256, 0, stream>>>(pos, neg, bufB, out, EP);
}

// Round 2
// 715.248 us; speedup vs baseline: 1.2878x; 1.2878x over previous
//
#include <hip/hip_runtime.h>

// ---------------------------------------------------------------------------
// EdgeNet: 2-layer GCN encode + dot-product edge decode, all fp32.
// Pipeline: deg count -> dinv -> 3-phase scan (CSR rowptr) -> fill CSR ->
//           GEMM1 -> agg+bias+relu -> GEMM2 -> agg+bias -> edge dot decode.
// R2: replaced 231us single-block scan with multi-block 3-phase scan.
// ---------------------------------------------------------------------------

#define SCAN_CH 512  // elements per block in scan phases 1/3

__global__ __launch_bounds__(256) void count_deg_k(const int* __restrict__ dst, int E,
                                                   int* __restrict__ deg) {
  int i = blockIdx.x * 256 + threadIdx.x;
  if (i < E) atomicAdd(&deg[dst[i]], 1);
}

__global__ __launch_bounds__(256) void dinv_k(const int* __restrict__ deg,
                                              float* __restrict__ dinv, int n) {
  int i = blockIdx.x * 256 + threadIdx.x;
  if (i < n) dinv[i] = rsqrtf((float)(deg[i] + 1));  // +1 self-loop
}

// --- scan phase 1: per-block sums of SCAN_CH counts ---
__global__ __launch_bounds__(256) void block_sum_k(const int* __restrict__ cnt, int n,
                                                   int* __restrict__ sums) {
  __shared__ int tsum[256];
  const int b = blockIdx.x, t = threadIdx.x;
  const int base = b * SCAN_CH + t * 2;
  int s = 0;
  if (base < n) s += cnt[base];
  if (base + 1 < n) s += cnt[base + 1];
  tsum[t] = s;
  __syncthreads();
  for (int off = 128; off > 0; off >>= 1) {
    if (t < off) tsum[t] += tsum[t + off];
    __syncthreads();
  }
  if (t == 0) sums[b] = tsum[0];
}

// --- scan phase 2: single small block scans the ~196 block sums in place ---
__global__ __launch_bounds__(256) void scan_sums_k(int* __restrict__ sums, int nb,
                                                   int n, int* __restrict__ rowptr) {
  __shared__ int arr[256];
  const int t = threadIdx.x;
  const int per = (nb + 255) / 256;
  const int start = t * per;
  const int end = min(start + per, nb);
  int s = 0;
  for (int i = start; i < end; ++i) s += sums[i];
  arr[t] = s;
  __syncthreads();
  for (int off = 1; off < 256; off <<= 1) {
    int v = (t >= off) ? arr[t - off] : 0;
    __syncthreads();
    arr[t] += v;
    __syncthreads();
  }
  int run = arr[t] - s;  // exclusive prefix
  for (int i = start; i < end; ++i) {
    int c = sums[i];
    sums[i] = run;  // overwrite with exclusive block offset
    run += c;
  }
  if (t == 255) rowptr[n] = arr[255];  // total == E
}

// --- scan phase 3: per-block rescan, emit rowptr + cursor ---
__global__ __launch_bounds__(256) void scan_fill_k(const int* __restrict__ cnt, int n,
                                                   const int* __restrict__ blockoff,
                                                   int* __restrict__ rowptr,
                                                   int* __restrict__ cursor) {
  __shared__ int tsum[256];
  const int b = blockIdx.x, t = threadIdx.x;
  const int base = b * SCAN_CH + t * 2;
  const int c0 = (base < n) ? cnt[base] : 0;
  const int c1 = (base + 1 < n) ? cnt[base + 1] : 0;
  const int s = c0 + c1;
  tsum[t] = s;
  __syncthreads();
  for (int off = 1; off < 256; off <<= 1) {
    int v = (t >= off) ? tsum[t - off] : 0;
    __syncthreads();
    tsum[t] += v;
    __syncthreads();
  }
  const int pre = blockoff[b] + tsum[t] - s;  // exclusive prefix for elem base
  if (base < n) {
    rowptr[base] = pre;
    cursor[base] = pre;
  }
  if (base + 1 < n) {
    rowptr[base + 1] = pre + c0;
    cursor[base + 1] = pre + c0;
  }
}

__global__ __launch_bounds__(256) void fill_csr_k(const int* __restrict__ src,
                                                  const int* __restrict__ dst, int E,
                                                  int* __restrict__ cursor,
                                                  int* __restrict__ csr_src) {
  int i = blockIdx.x * 256 + threadIdx.x;
  if (i < E) {
    int d = dst[i];
    int pos = atomicAdd(&cursor[d], 1);
    csr_src[pos] = src[i];
  }
}

// ---------------------------------------------------------------------------
// fp32 tiled GEMM: C[M,N] = A[M,K] @ B[K,N].  Block = (BM/TM)*(BN/TN) = 256.
// ---------------------------------------------------------------------------
template <int BM, int BN, int BK, int TM, int TN>
__global__ __launch_bounds__(256) void gemm_tiled(const float* __restrict__ A,
                                                  const float* __restrict__ B,
                                                  float* __restrict__ C, int M, int K,
                                                  int N) {
  __shared__ float As[BK][BM];  // transposed A tile
  __shared__ float Bs[BK][BN];
  const int tid = threadIdx.x;
  const int tx = tid % (BN / TN);
  const int ty = tid / (BN / TN);
  const int rowBase = blockIdx.x * BM;
  const int colBase = blockIdx.y * BN;

  float acc[TM][TN];
#pragma unroll
  for (int i = 0; i < TM; ++i)
#pragma unroll
    for (int j = 0; j < TN; ++j) acc[i][j] = 0.f;

  for (int k0 = 0; k0 < K; k0 += BK) {
    {
      const int arow = tid / (BK / 4);
      const int acol4 = (tid % (BK / 4)) * 4;
      const int gr = rowBase + arow;
      float4 v;
      if (gr < M)
        v = *reinterpret_cast<const float4*>(&A[(size_t)gr * K + k0 + acol4]);
      else
        v = make_float4(0.f, 0.f, 0.f, 0.f);
      As[acol4 + 0][arow] = v.x;
      As[acol4 + 1][arow] = v.y;
      As[acol4 + 2][arow] = v.z;
      As[acol4 + 3][arow] = v.w;
    }
    for (int i = tid; i < BK * BN / 4; i += 256) {
      const int brow = i / (BN / 4);
      const int bcol4 = (i % (BN / 4)) * 4;
      float4 v = *reinterpret_cast<const float4*>(
          &B[(size_t)(k0 + brow) * N + colBase + bcol4]);
      *reinterpret_cast<float4*>(&Bs[brow][bcol4]) = v;
    }
    __syncthreads();
#pragma unroll
    for (int kk = 0; kk < BK; ++kk) {
      float ra[TM], rb[TN];
#pragma unroll
      for (int i = 0; i < TM; ++i) ra[i] = As[kk][ty * TM + i];
#pragma unroll
      for (int j = 0; j < TN; ++j) rb[j] = Bs[kk][tx * TN + j];
#pragma unroll
      for (int i = 0; i < TM; ++i)
#pragma unroll
        for (int j = 0; j < TN; ++j) acc[i][j] += ra[i] * rb[j];
    }
    __syncthreads();
  }
#pragma unroll
  for (int i = 0; i < TM; ++i) {
    const int gr = rowBase + ty * TM + i;
    if (gr < M) {
#pragma unroll
      for (int j = 0; j < TN; j += 4) {
        float4 v = {acc[i][j], acc[i][j + 1], acc[i][j + 2], acc[i][j + 3]};
        *reinterpret_cast<float4*>(&C[(size_t)gr * N + colBase + tx * TN + j]) = v;
      }
    }
  }
}

// ---------------------------------------------------------------------------
// Wave-per-node normalized aggregation (+ self loop, + bias, optional ReLU).
// ---------------------------------------------------------------------------
template <int C, bool RELU>
__global__ __launch_bounds__(256) void agg_k(const float* __restrict__ hin,
                                             const int* __restrict__ rowptr,
                                             const int* __restrict__ csr_src,
                                             const float* __restrict__ dinv,
                                             const float* __restrict__ bias,
                                             float* __restrict__ hout, int n) {
  const int wid = (blockIdx.x * blockDim.x + threadIdx.x) >> 6;
  const int lane = threadIdx.x & 63;
  if (wid >= n) return;
  const float dd = dinv[wid];
  const int beg = rowptr[wid];
  const int end = rowptr[wid + 1];
  if (C == 128) {
    float2 acc = {0.f, 0.f};
    for (int e = beg; e < end; ++e) {
      const int s = csr_src[e];
      const float w = dinv[s] * dd;
      const float2 v = *reinterpret_cast<const float2*>(&hin[(size_t)s * 128 + lane * 2]);
      acc.x += v.x * w;
      acc.y += v.y * w;
    }
    {
      const float w = dd * dd;
      const float2 v =
          *reinterpret_cast<const float2*>(&hin[(size_t)wid * 128 + lane * 2]);
      acc.x += v.x * w;
      acc.y += v.y * w;
    }
    const float2 b = *reinterpret_cast<const float2*>(&bias[lane * 2]);
    acc.x += b.x;
    acc.y += b.y;
    if (RELU) {
      acc.x = fmaxf(acc.x, 0.f);
      acc.y = fmaxf(acc.y, 0.f);
    }
    *reinterpret_cast<float2*>(&hout[(size_t)wid * 128 + lane * 2]) = acc;
  } else {  // C == 64
    float acc = 0.f;
    for (int e = beg; e < end; ++e) {
      const int s = csr_src[e];
      acc += hin[(size_t)s * 64 + lane] * (dinv[s] * dd);
    }
    acc += hin[(size_t)wid * 64 + lane] * (dd * dd);
    acc += bias[lane];
    hout[(size_t)wid * 64 + lane] = acc;
  }
}

// ---------------------------------------------------------------------------
// Decode: 16 lanes per edge, float4 chunks of z[.,64], shuffle reduce.
// ---------------------------------------------------------------------------
__global__ __launch_bounds__(256) void decode_k(const int* __restrict__ pos,
                                                const int* __restrict__ neg,
                                                const float* __restrict__ z,
                                                float* __restrict__ out, int EP) {
  const long long t = (long long)blockIdx.x * 256 + threadIdx.x;
  const long long e = t >> 4;
  const int lane = (int)(t & 15);
  if (e >= 2LL * EP) return;
  int u, v;
  if (e < EP) {
    u = pos[e];
    v = pos[EP + e];
  } else {
    u = neg[e - EP];
    v = neg[EP + (e - EP)];
  }
  const float4 a = *reinterpret_cast<const float4*>(&z[(size_t)u * 64 + lane * 4]);
  const float4 b = *reinterpret_cast<const float4*>(&z[(size_t)v * 64 + lane * 4]);
  float p = a.x * b.x + a.y * b.y + a.z * b.z + a.w * b.w;
#pragma unroll
  for (int off = 8; off > 0; off >>= 1) p += __shfl_down(p, off, 16);
  if (lane == 0) out[e] = p;
}

// ---------------------------------------------------------------------------

extern "C" void kernel_launch(void* const* d_in, const int* in_sizes, int n_in,
                              void* d_out, int out_size, void* d_ws, size_t ws_size,
                              hipStream_t stream) {
  const float* x = (const float*)d_in[0];
  const int* ei = (const int*)d_in[1];
  const int* pos = (const int*)d_in[2];
  const int* neg = (const int*)d_in[3];
  const float* W1 = (const float*)d_in[4];
  const float* b1 = (const float*)d_in[5];
  const float* W2 = (const float*)d_in[6];
  const float* b2 = (const float*)d_in[7];
  float* out = (float*)d_out;

  const int H = in_sizes[5];        // 128
  const int IN = in_sizes[4] / H;   // 256
  const int OUT = in_sizes[7];      // 64
  const int N = in_sizes[0] / IN;   // 100000
  const int E = in_sizes[1] / 2;    // 1600000
  const int EP = in_sizes[2] / 2;   // 500000

  char* ws = (char*)d_ws;
  size_t off = 0;
  auto carve = [&](size_t bytes) -> char* {
    char* p = ws + off;
    off += (bytes + 255) & ~(size_t)255;
    return p;
  };
  const int NB = (N + SCAN_CH - 1) / SCAN_CH;
  int* degi = (int*)carve((size_t)N * 4);
  float* dinvb = (float*)carve((size_t)N * 4);
  int* rowptr = (int*)carve((size_t)(N + 1) * 4);
  int* cursor = (int*)carve((size_t)N * 4);
  int* bsums = (int*)carve((size_t)NB * 4);
  int* csr = (int*)carve((size_t)E * 4);
  float* bufA = (float*)carve((size_t)N * H * 4);
  float* bufB = (float*)carve((size_t)N * H * 4);
  (void)ws_size;

  const int* srcp = ei;
  const int* dstp = ei + E;

  hipMemsetAsync(degi, 0, (size_t)N * 4, stream);
  count_deg_k<<<(E + 255) / 256, 256, 0, stream>>>(dstp, E, degi);
  dinv_k<<<(N + 255) / 256, 256, 0, stream>>>(degi, dinvb, N);
  // 3-phase scan: counts -> rowptr/cursor
  block_sum_k<<<NB, 256, 0, stream>>>(degi, N, bsums);
  scan_sums_k<<<1, 256, 0, stream>>>(bsums, NB, N, rowptr);
  scan_fill_k<<<NB, 256, 0, stream>>>(degi, N, bsums, rowptr, cursor);
  fill_csr_k<<<(E + 255) / 256, 256, 0, stream>>>(srcp, dstp, E, cursor, csr);

  // GEMM1: h0 = x @ W1   [N,256]@[256,128]
  gemm_tiled<64, 128, 16, 4, 8>
      <<<dim3((N + 63) / 64, 1), 256, 0, stream>>>(x, W1, bufA, N, IN, H);
  // agg1: h = relu(scatter(h0*norm) + b1)
  agg_k<128, true><<<(N + 3) / 4, 256, 0, stream>>>(bufA, rowptr, csr, dinvb, b1,
                                                    bufB, N);
  // GEMM2: h1 = h @ W2   [N,128]@[128,64]
  gemm_tiled<64, 64, 16, 4, 4>
      <<<dim3((N + 63) / 64, 1), 256, 0, stream>>>(bufB, W2, bufA, N, H, OUT);
  // agg2: z = scatter(h1*norm) + b2
  agg_k<64, false><<<(N + 3) / 4, 256, 0, stream>>>(bufA, rowptr, csr, dinvb, b2,
                                                    bufB, N);
  // decode: out[e] = <z_u, z_v>
  const long long threads = 2LL * EP * 16;
  decode_k<<<(int)((threads + 255) / 256), 256, 0, stream>>>(pos, neg, bufB, out, EP);
}

// Round 3
// 586.526 us; speedup vs baseline: 1.5704x; 1.2195x over previous
//
#include <hip/hip_runtime.h>

// ---------------------------------------------------------------------------
// EdgeNet: 2-layer GCN encode + dot-product edge decode, all fp32.
// R3: dinv folded into GEMM epilogue (agg = pure gather-sum), agg loop
//     unrolled x4 (4 gathers in flight), 128-wide GEMM tiles with 8x8
//     micro-tiles and BK=32.
// ---------------------------------------------------------------------------

#define SCAN_CH 512

__global__ __launch_bounds__(256) void count_deg_k(const int* __restrict__ dst, int E,
                                                   int* __restrict__ deg) {
  int i = blockIdx.x * 256 + threadIdx.x;
  if (i < E) atomicAdd(&deg[dst[i]], 1);
}

__global__ __launch_bounds__(256) void dinv_k(const int* __restrict__ deg,
                                              float* __restrict__ dinv, int n) {
  int i = blockIdx.x * 256 + threadIdx.x;
  if (i < n) dinv[i] = rsqrtf((float)(deg[i] + 1));  // +1 self-loop
}

// --- 3-phase scan ---
__global__ __launch_bounds__(256) void block_sum_k(const int* __restrict__ cnt, int n,
                                                   int* __restrict__ sums) {
  __shared__ int tsum[256];
  const int b = blockIdx.x, t = threadIdx.x;
  const int base = b * SCAN_CH + t * 2;
  int s = 0;
  if (base < n) s += cnt[base];
  if (base + 1 < n) s += cnt[base + 1];
  tsum[t] = s;
  __syncthreads();
  for (int off = 128; off > 0; off >>= 1) {
    if (t < off) tsum[t] += tsum[t + off];
    __syncthreads();
  }
  if (t == 0) sums[b] = tsum[0];
}

__global__ __launch_bounds__(256) void scan_sums_k(int* __restrict__ sums, int nb,
                                                   int n, int* __restrict__ rowptr) {
  __shared__ int arr[256];
  const int t = threadIdx.x;
  const int per = (nb + 255) / 256;
  const int start = t * per;
  const int end = min(start + per, nb);
  int s = 0;
  for (int i = start; i < end; ++i) s += sums[i];
  arr[t] = s;
  __syncthreads();
  for (int off = 1; off < 256; off <<= 1) {
    int v = (t >= off) ? arr[t - off] : 0;
    __syncthreads();
    arr[t] += v;
    __syncthreads();
  }
  int run = arr[t] - s;
  for (int i = start; i < end; ++i) {
    int c = sums[i];
    sums[i] = run;
    run += c;
  }
  if (t == 255) rowptr[n] = arr[255];
}

__global__ __launch_bounds__(256) void scan_fill_k(const int* __restrict__ cnt, int n,
                                                   const int* __restrict__ blockoff,
                                                   int* __restrict__ rowptr,
                                                   int* __restrict__ cursor) {
  __shared__ int tsum[256];
  const int b = blockIdx.x, t = threadIdx.x;
  const int base = b * SCAN_CH + t * 2;
  const int c0 = (base < n) ? cnt[base] : 0;
  const int c1 = (base + 1 < n) ? cnt[base + 1] : 0;
  const int s = c0 + c1;
  tsum[t] = s;
  __syncthreads();
  for (int off = 1; off < 256; off <<= 1) {
    int v = (t >= off) ? tsum[t - off] : 0;
    __syncthreads();
    tsum[t] += v;
    __syncthreads();
  }
  const int pre = blockoff[b] + tsum[t] - s;
  if (base < n) {
    rowptr[base] = pre;
    cursor[base] = pre;
  }
  if (base + 1 < n) {
    rowptr[base + 1] = pre + c0;
    cursor[base + 1] = pre + c0;
  }
}

__global__ __launch_bounds__(256) void fill_csr_k(const int* __restrict__ src,
                                                  const int* __restrict__ dst, int E,
                                                  int* __restrict__ cursor,
                                                  int* __restrict__ csr_src) {
  int i = blockIdx.x * 256 + threadIdx.x;
  if (i < E) {
    int d = dst[i];
    int pos = atomicAdd(&cursor[d], 1);
    csr_src[pos] = src[i];
  }
}

// ---------------------------------------------------------------------------
// fp32 tiled GEMM, C[M,N] = rowscale[m] * (A[M,K] @ B[K,N]).
// BM/TM * BN/TN == 256 threads. BN == N (single block column).
// LDS A-tile transposed with +4 pad: conflict-free aligned b128 reads,
// 4-way conflict only on the 16 staging stores per k-step (negligible).
// ---------------------------------------------------------------------------
template <int BM, int BN, int BK, int TM, int TN>
__global__ __launch_bounds__(256) void gemm_tiled(const float* __restrict__ A,
                                                  const float* __restrict__ B,
                                                  float* __restrict__ C,
                                                  const float* __restrict__ rowscale,
                                                  int M, int K, int N) {
  __shared__ float As[BK][BM + 4];
  __shared__ float Bs[BK][BN];
  const int tid = threadIdx.x;
  const int tx = tid % (BN / TN);
  const int ty = tid / (BN / TN);
  const int rowBase = blockIdx.x * BM;

  float acc[TM][TN];
#pragma unroll
  for (int i = 0; i < TM; ++i)
#pragma unroll
    for (int j = 0; j < TN; ++j) acc[i][j] = 0.f;

  for (int k0 = 0; k0 < K; k0 += BK) {
#pragma unroll
    for (int l = 0; l < BM * BK / (4 * 256); ++l) {
      const int idx = tid + l * 256;
      const int arow = idx / (BK / 4);
      const int acol4 = (idx % (BK / 4)) * 4;
      const int gr = rowBase + arow;
      float4 v;
      if (gr < M)
        v = *reinterpret_cast<const float4*>(&A[(size_t)gr * K + k0 + acol4]);
      else
        v = make_float4(0.f, 0.f, 0.f, 0.f);
      As[acol4 + 0][arow] = v.x;
      As[acol4 + 1][arow] = v.y;
      As[acol4 + 2][arow] = v.z;
      As[acol4 + 3][arow] = v.w;
    }
#pragma unroll
    for (int l = 0; l < BK * BN / (4 * 256); ++l) {
      const int idx = tid + l * 256;
      const int brow = idx / (BN / 4);
      const int bcol4 = (idx % (BN / 4)) * 4;
      *reinterpret_cast<float4*>(&Bs[brow][bcol4]) =
          *reinterpret_cast<const float4*>(&B[(size_t)(k0 + brow) * N + bcol4]);
    }
    __syncthreads();
#pragma unroll
    for (int kk = 0; kk < BK; ++kk) {
      float ra[TM], rb[TN];
#pragma unroll
      for (int i = 0; i < TM; ++i) ra[i] = As[kk][ty * TM + i];
#pragma unroll
      for (int j = 0; j < TN; ++j) rb[j] = Bs[kk][tx * TN + j];
#pragma unroll
      for (int i = 0; i < TM; ++i)
#pragma unroll
        for (int j = 0; j < TN; ++j) acc[i][j] += ra[i] * rb[j];
    }
    __syncthreads();
  }
#pragma unroll
  for (int i = 0; i < TM; ++i) {
    const int gr = rowBase + ty * TM + i;
    if (gr < M) {
      const float s = rowscale ? rowscale[gr] : 1.f;
#pragma unroll
      for (int j = 0; j < TN; j += 4) {
        float4 v = {acc[i][j] * s, acc[i][j + 1] * s, acc[i][j + 2] * s,
                    acc[i][j + 3] * s};
        *reinterpret_cast<float4*>(&C[(size_t)gr * N + tx * TN + j]) = v;
      }
    }
  }
}

// ---------------------------------------------------------------------------
// Aggregation over pre-scaled features g = dinv[i]*h[i]:
//   out[d] = RELU?( dinv[d] * (sum_{s in N(d)} g[s] + g[d]) + bias )
// Pure gather-sum, unrolled x4 for memory-level parallelism.
// ---------------------------------------------------------------------------
template <int C, bool RELU>
__global__ __launch_bounds__(256) void agg_k(const float* __restrict__ g,
                                             const int* __restrict__ rowptr,
                                             const int* __restrict__ csr_src,
                                             const float* __restrict__ dinv,
                                             const float* __restrict__ bias,
                                             float* __restrict__ hout, int n) {
  const int wid = (blockIdx.x * blockDim.x + threadIdx.x) >> 6;
  const int lane = threadIdx.x & 63;
  if (wid >= n) return;
  const float dd = dinv[wid];
  const int beg = rowptr[wid];
  const int end = rowptr[wid + 1];
  if (C == 128) {
    const size_t col = (size_t)lane * 2;
    float2 acc = *reinterpret_cast<const float2*>(&g[(size_t)wid * 128 + col]);
    int e = beg;
    for (; e + 4 <= end; e += 4) {
      const int s0 = csr_src[e + 0];
      const int s1 = csr_src[e + 1];
      const int s2 = csr_src[e + 2];
      const int s3 = csr_src[e + 3];
      const float2 v0 = *reinterpret_cast<const float2*>(&g[(size_t)s0 * 128 + col]);
      const float2 v1 = *reinterpret_cast<const float2*>(&g[(size_t)s1 * 128 + col]);
      const float2 v2 = *reinterpret_cast<const float2*>(&g[(size_t)s2 * 128 + col]);
      const float2 v3 = *reinterpret_cast<const float2*>(&g[(size_t)s3 * 128 + col]);
      acc.x += (v0.x + v1.x) + (v2.x + v3.x);
      acc.y += (v0.y + v1.y) + (v2.y + v3.y);
    }
    for (; e < end; ++e) {
      const int s = csr_src[e];
      const float2 v = *reinterpret_cast<const float2*>(&g[(size_t)s * 128 + col]);
      acc.x += v.x;
      acc.y += v.y;
    }
    const float2 b = *reinterpret_cast<const float2*>(&bias[col]);
    float rx = dd * acc.x + b.x;
    float ry = dd * acc.y + b.y;
    if (RELU) {
      rx = fmaxf(rx, 0.f);
      ry = fmaxf(ry, 0.f);
    }
    *reinterpret_cast<float2*>(&hout[(size_t)wid * 128 + col]) = make_float2(rx, ry);
  } else {  // C == 64
    float acc = g[(size_t)wid * 64 + lane];
    int e = beg;
    for (; e + 4 <= end; e += 4) {
      const int s0 = csr_src[e + 0];
      const int s1 = csr_src[e + 1];
      const int s2 = csr_src[e + 2];
      const int s3 = csr_src[e + 3];
      const float v0 = g[(size_t)s0 * 64 + lane];
      const float v1 = g[(size_t)s1 * 64 + lane];
      const float v2 = g[(size_t)s2 * 64 + lane];
      const float v3 = g[(size_t)s3 * 64 + lane];
      acc += (v0 + v1) + (v2 + v3);
    }
    for (; e < end; ++e) acc += g[(size_t)csr_src[e] * 64 + lane];
    hout[(size_t)wid * 64 + lane] = dd * acc + bias[lane];
  }
}

// ---------------------------------------------------------------------------
// Decode: 16 lanes per edge, float4 chunks of z[.,64], shuffle reduce.
// ---------------------------------------------------------------------------
__global__ __launch_bounds__(256) void decode_k(const int* __restrict__ pos,
                                                const int* __restrict__ neg,
                                                const float* __restrict__ z,
                                                float* __restrict__ out, int EP) {
  const long long t = (long long)blockIdx.x * 256 + threadIdx.x;
  const long long e = t >> 4;
  const int lane = (int)(t & 15);
  if (e >= 2LL * EP) return;
  int u, v;
  if (e < EP) {
    u = pos[e];
    v = pos[EP + e];
  } else {
    u = neg[e - EP];
    v = neg[EP + (e - EP)];
  }
  const float4 a = *reinterpret_cast<const float4*>(&z[(size_t)u * 64 + lane * 4]);
  const float4 b = *reinterpret_cast<const float4*>(&z[(size_t)v * 64 + lane * 4]);
  float p = a.x * b.x + a.y * b.y + a.z * b.z + a.w * b.w;
#pragma unroll
  for (int off = 8; off > 0; off >>= 1) p += __shfl_down(p, off, 16);
  if (lane == 0) out[e] = p;
}

// ---------------------------------------------------------------------------

extern "C" void kernel_launch(void* const* d_in, const int* in_sizes, int n_in,
                              void* d_out, int out_size, void* d_ws, size_t ws_size,
                              hipStream_t stream) {
  const float* x = (const float*)d_in[0];
  const int* ei = (const int*)d_in[1];
  const int* pos = (const int*)d_in[2];
  const int* neg = (const int*)d_in[3];
  const float* W1 = (const float*)d_in[4];
  const float* b1 = (const float*)d_in[5];
  const float* W2 = (const float*)d_in[6];
  const float* b2 = (const float*)d_in[7];
  float* out = (float*)d_out;

  const int H = in_sizes[5];        // 128
  const int IN = in_sizes[4] / H;   // 256
  const int OUT = in_sizes[7];      // 64
  const int N = in_sizes[0] / IN;   // 100000
  const int E = in_sizes[1] / 2;    // 1600000
  const int EP = in_sizes[2] / 2;   // 500000

  char* ws = (char*)d_ws;
  size_t off = 0;
  auto carve = [&](size_t bytes) -> char* {
    char* p = ws + off;
    off += (bytes + 255) & ~(size_t)255;
    return p;
  };
  const int NB = (N + SCAN_CH - 1) / SCAN_CH;
  int* degi = (int*)carve((size_t)N * 4);
  float* dinvb = (float*)carve((size_t)N * 4);
  int* rowptr = (int*)carve((size_t)(N + 1) * 4);
  int* cursor = (int*)carve((size_t)N * 4);
  int* bsums = (int*)carve((size_t)NB * 4);
  int* csr = (int*)carve((size_t)E * 4);
  float* bufA = (float*)carve((size_t)N * H * 4);
  float* bufB = (float*)carve((size_t)N * H * 4);
  (void)ws_size;

  const int* srcp = ei;
  const int* dstp = ei + E;

  hipMemsetAsync(degi, 0, (size_t)N * 4, stream);
  count_deg_k<<<(E + 255) / 256, 256, 0, stream>>>(dstp, E, degi);
  dinv_k<<<(N + 255) / 256, 256, 0, stream>>>(degi, dinvb, N);
  block_sum_k<<<NB, 256, 0, stream>>>(degi, N, bsums);
  scan_sums_k<<<1, 256, 0, stream>>>(bsums, NB, N, rowptr);
  scan_fill_k<<<NB, 256, 0, stream>>>(degi, N, bsums, rowptr, cursor);
  fill_csr_k<<<(E + 255) / 256, 256, 0, stream>>>(srcp, dstp, E, cursor, csr);

  // GEMM1: g1 = dinv * (x @ W1)   [N,256]@[256,128], pre-scaled rows
  gemm_tiled<128, 128, 32, 8, 8>
      <<<(N + 127) / 128, 256, 0, stream>>>(x, W1, bufA, dinvb, N, IN, H);
  // agg1: h = relu(dinv * (gather-sum g1) + b1)
  agg_k<128, true><<<(N + 3) / 4, 256, 0, stream>>>(bufA, rowptr, csr, dinvb, b1,
                                                    bufB, N);
  // GEMM2: g2 = dinv * (h @ W2)   [N,128]@[128,64]
  gemm_tiled<128, 64, 32, 8, 4>
      <<<(N + 127) / 128, 256, 0, stream>>>(bufB, W2, bufA, dinvb, N, H, OUT);
  // agg2: z = dinv * (gather-sum g2) + b2
  agg_k<64, false><<<(N + 3) / 4, 256, 0, stream>>>(bufA, rowptr, csr, dinvb, b2,
                                                    bufB, N);
  // decode
  const long long threads = 2LL * EP * 16;
  decode_k<<<(int)((threads + 255) / 256), 256, 0, stream>>>(pos, neg, bufB, out, EP);
}

// Round 4
// 488.509 us; speedup vs baseline: 1.8855x; 1.2006x over previous
//
#include <hip/hip_runtime.h>

// ---------------------------------------------------------------------------
// EdgeNet: 2-layer GCN encode + dot-product edge decode, all fp32.
// R4: (a) CSR build via dst-bucketing (782 buckets x 128 nodes): LDS
//     histograms + block-reserved scatter + per-bucket LDS-cursor fill.
//     Kills the 16x write amplification of the old random fill_csr.
//     (b) GEMM LDS layout As[BM][BK+1] (odd stride): conflict-free reads,
//     ~2-way staging stores; BK=16 halves LDS -> better occupancy.
// ---------------------------------------------------------------------------

#define SCAN_CH 512
#define BUK_SHIFT 7
#define BUK_NODES 128  // nodes per bucket

// --- edge bucketing -------------------------------------------------------
__global__ __launch_bounds__(256) void b_hist_k(const int* __restrict__ dst, int E,
                                                int nbuk, int* __restrict__ bhist) {
  __shared__ int h[1024];
  for (int i = threadIdx.x; i < nbuk; i += 256) h[i] = 0;
  __syncthreads();
  for (int i = blockIdx.x * 256 + threadIdx.x; i < E; i += gridDim.x * 256)
    atomicAdd(&h[dst[i] >> BUK_SHIFT], 1);
  __syncthreads();
  for (int i = threadIdx.x; i < nbuk; i += 256) {
    int c = h[i];
    if (c) atomicAdd(&bhist[i], c);
  }
}

__global__ __launch_bounds__(256) void b_scan_k(const int* __restrict__ bhist,
                                                int nbuk, int* __restrict__ bbase,
                                                int* __restrict__ bcur) {
  __shared__ int arr[256];
  const int t = threadIdx.x;
  const int per = (nbuk + 255) / 256;
  const int start = t * per;
  const int end = min(start + per, nbuk);
  int s = 0;
  for (int i = start; i < end; ++i) s += bhist[i];
  arr[t] = s;
  __syncthreads();
  for (int off = 1; off < 256; off <<= 1) {
    int v = (t >= off) ? arr[t - off] : 0;
    __syncthreads();
    arr[t] += v;
    __syncthreads();
  }
  int run = arr[t] - s;
  for (int i = start; i < end; ++i) {
    bbase[i] = run;
    bcur[i] = run;
    run += bhist[i];
  }
  if (t == 255) bbase[nbuk] = arr[255];
}

// chunk of 8192 edges per block; LDS hist -> reserve -> scatter int2 pairs
__global__ __launch_bounds__(256) void b_scatter_k(const int* __restrict__ src,
                                                   const int* __restrict__ dst, int E,
                                                   int nbuk, int* __restrict__ bcur,
                                                   int2* __restrict__ ebuf) {
  __shared__ int lh[1024];
  __shared__ int lc[1024];
  const int base = blockIdx.x * 8192;
  if (base >= E) return;
  const int end = min(base + 8192, E);
  for (int i = threadIdx.x; i < nbuk; i += 256) lh[i] = 0;
  __syncthreads();
  for (int i = base + threadIdx.x; i < end; i += 256)
    atomicAdd(&lh[dst[i] >> BUK_SHIFT], 1);
  __syncthreads();
  for (int i = threadIdx.x; i < nbuk; i += 256) {
    int c = lh[i];
    lc[i] = c ? atomicAdd(&bcur[i], c) : 0;
  }
  __syncthreads();
  for (int i = base + threadIdx.x; i < end; i += 256) {
    int d = dst[i];
    int pos = atomicAdd(&lc[d >> BUK_SHIFT], 1);
    ebuf[pos] = make_int2(src[i], d);
  }
}

// one block per bucket: degree count in LDS, write deg + dinv coalesced
__global__ __launch_bounds__(128) void b_deg_k(const int2* __restrict__ ebuf,
                                               const int* __restrict__ bbase, int n,
                                               int* __restrict__ deg,
                                               float* __restrict__ dinv) {
  __shared__ int cnt[BUK_NODES];
  const int b = blockIdx.x;
  cnt[threadIdx.x] = 0;
  __syncthreads();
  const int beg = bbase[b], end = bbase[b + 1];
  for (int i = beg + threadIdx.x; i < end; i += 128)
    atomicAdd(&cnt[ebuf[i].y & (BUK_NODES - 1)], 1);
  __syncthreads();
  const int node = (b << BUK_SHIFT) + threadIdx.x;
  if (node < n) {
    int c = cnt[threadIdx.x];
    deg[node] = c;
    dinv[node] = rsqrtf((float)(c + 1));  // +1 self-loop
  }
}

// one block per bucket: CSR fill with LDS cursors (no global atomics)
__global__ __launch_bounds__(128) void b_fill_k(const int2* __restrict__ ebuf,
                                                const int* __restrict__ bbase,
                                                const int* __restrict__ rowptr, int n,
                                                int* __restrict__ csr) {
  __shared__ int cur[BUK_NODES];
  const int b = blockIdx.x;
  const int node = (b << BUK_SHIFT) + threadIdx.x;
  cur[threadIdx.x] = (node < n) ? rowptr[node] : 0;
  __syncthreads();
  const int beg = bbase[b], end = bbase[b + 1];
  for (int i = beg + threadIdx.x; i < end; i += 128) {
    int2 e = ebuf[i];
    int pos = atomicAdd(&cur[e.y & (BUK_NODES - 1)], 1);
    csr[pos] = e.x;
  }
}

// --- 3-phase scan over node degrees -> rowptr -----------------------------
__global__ __launch_bounds__(256) void block_sum_k(const int* __restrict__ cnt, int n,
                                                   int* __restrict__ sums) {
  __shared__ int tsum[256];
  const int b = blockIdx.x, t = threadIdx.x;
  const int base = b * SCAN_CH + t * 2;
  int s = 0;
  if (base < n) s += cnt[base];
  if (base + 1 < n) s += cnt[base + 1];
  tsum[t] = s;
  __syncthreads();
  for (int off = 128; off > 0; off >>= 1) {
    if (t < off) tsum[t] += tsum[t + off];
    __syncthreads();
  }
  if (t == 0) sums[b] = tsum[0];
}

__global__ __launch_bounds__(256) void scan_sums_k(int* __restrict__ sums, int nb,
                                                   int n, int* __restrict__ rowptr) {
  __shared__ int arr[256];
  const int t = threadIdx.x;
  const int per = (nb + 255) / 256;
  const int start = t * per;
  const int end = min(start + per, nb);
  int s = 0;
  for (int i = start; i < end; ++i) s += sums[i];
  arr[t] = s;
  __syncthreads();
  for (int off = 1; off < 256; off <<= 1) {
    int v = (t >= off) ? arr[t - off] : 0;
    __syncthreads();
    arr[t] += v;
    __syncthreads();
  }
  int run = arr[t] - s;
  for (int i = start; i < end; ++i) {
    int c = sums[i];
    sums[i] = run;
    run += c;
  }
  if (t == 255) rowptr[n] = arr[255];
}

__global__ __launch_bounds__(256) void scan_fill_k(const int* __restrict__ cnt, int n,
                                                   const int* __restrict__ blockoff,
                                                   int* __restrict__ rowptr) {
  __shared__ int tsum[256];
  const int b = blockIdx.x, t = threadIdx.x;
  const int base = b * SCAN_CH + t * 2;
  const int c0 = (base < n) ? cnt[base] : 0;
  const int c1 = (base + 1 < n) ? cnt[base + 1] : 0;
  const int s = c0 + c1;
  tsum[t] = s;
  __syncthreads();
  for (int off = 1; off < 256; off <<= 1) {
    int v = (t >= off) ? tsum[t - off] : 0;
    __syncthreads();
    tsum[t] += v;
    __syncthreads();
  }
  const int pre = blockoff[b] + tsum[t] - s;
  if (base < n) rowptr[base] = pre;
  if (base + 1 < n) rowptr[base + 1] = pre + c0;
}

// ---------------------------------------------------------------------------
// fp32 tiled GEMM, C[M,N] = rowscale[m] * (A[M,K] @ B[K,N]).  BN == N.
// As[BM][BK+1]: odd stride -> conflict-free broadcast reads, ~2-way stores.
// ---------------------------------------------------------------------------
template <int BM, int BN, int BK, int TM, int TN>
__global__ __launch_bounds__(256) void gemm_tiled(const float* __restrict__ A,
                                                  const float* __restrict__ B,
                                                  float* __restrict__ C,
                                                  const float* __restrict__ rowscale,
                                                  int M, int K, int N) {
  __shared__ float As[BM][BK + 1];
  __shared__ float Bs[BK][BN];
  const int tid = threadIdx.x;
  const int tx = tid % (BN / TN);
  const int ty = tid / (BN / TN);
  const int rowBase = blockIdx.x * BM;

  float acc[TM][TN];
#pragma unroll
  for (int i = 0; i < TM; ++i)
#pragma unroll
    for (int j = 0; j < TN; ++j) acc[i][j] = 0.f;

  for (int k0 = 0; k0 < K; k0 += BK) {
#pragma unroll
    for (int l = 0; l < BM * BK / (4 * 256); ++l) {
      const int idx = tid + l * 256;
      const int arow = idx / (BK / 4);
      const int acol = (idx % (BK / 4)) * 4;
      const int gr = rowBase + arow;
      float4 v;
      if (gr < M)
        v = *reinterpret_cast<const float4*>(&A[(size_t)gr * K + k0 + acol]);
      else
        v = make_float4(0.f, 0.f, 0.f, 0.f);
      As[arow][acol + 0] = v.x;
      As[arow][acol + 1] = v.y;
      As[arow][acol + 2] = v.z;
      As[arow][acol + 3] = v.w;
    }
#pragma unroll
    for (int l = 0; l < BK * BN / (4 * 256); ++l) {
      const int idx = tid + l * 256;
      const int brow = idx / (BN / 4);
      const int bcol4 = (idx % (BN / 4)) * 4;
      *reinterpret_cast<float4*>(&Bs[brow][bcol4]) =
          *reinterpret_cast<const float4*>(&B[(size_t)(k0 + brow) * N + bcol4]);
    }
    __syncthreads();
#pragma unroll
    for (int kk = 0; kk < BK; ++kk) {
      float ra[TM], rb[TN];
#pragma unroll
      for (int i = 0; i < TM; ++i) ra[i] = As[ty * TM + i][kk];
#pragma unroll
      for (int j = 0; j < TN; ++j) rb[j] = Bs[kk][tx * TN + j];
#pragma unroll
      for (int i = 0; i < TM; ++i)
#pragma unroll
        for (int j = 0; j < TN; ++j) acc[i][j] += ra[i] * rb[j];
    }
    __syncthreads();
  }
#pragma unroll
  for (int i = 0; i < TM; ++i) {
    const int gr = rowBase + ty * TM + i;
    if (gr < M) {
      const float s = rowscale ? rowscale[gr] : 1.f;
#pragma unroll
      for (int j = 0; j < TN; j += 4) {
        float4 v = {acc[i][j] * s, acc[i][j + 1] * s, acc[i][j + 2] * s,
                    acc[i][j + 3] * s};
        *reinterpret_cast<float4*>(&C[(size_t)gr * N + tx * TN + j]) = v;
      }
    }
  }
}

// ---------------------------------------------------------------------------
// Aggregation over pre-scaled features g = dinv[i]*h[i]:
//   out[d] = RELU?( dinv[d] * (sum_{s in N(d)} g[s] + g[d]) + bias )
// ---------------------------------------------------------------------------
template <int C, bool RELU>
__global__ __launch_bounds__(256) void agg_k(const float* __restrict__ g,
                                             const int* __restrict__ rowptr,
                                             const int* __restrict__ csr_src,
                                             const float* __restrict__ dinv,
                                             const float* __restrict__ bias,
                                             float* __restrict__ hout, int n) {
  const int wid = (blockIdx.x * blockDim.x + threadIdx.x) >> 6;
  const int lane = threadIdx.x & 63;
  if (wid >= n) return;
  const float dd = dinv[wid];
  const int beg = rowptr[wid];
  const int end = rowptr[wid + 1];
  if (C == 128) {
    const size_t col = (size_t)lane * 2;
    float2 acc = *reinterpret_cast<const float2*>(&g[(size_t)wid * 128 + col]);
    int e = beg;
    for (; e + 4 <= end; e += 4) {
      const int s0 = csr_src[e + 0];
      const int s1 = csr_src[e + 1];
      const int s2 = csr_src[e + 2];
      const int s3 = csr_src[e + 3];
      const float2 v0 = *reinterpret_cast<const float2*>(&g[(size_t)s0 * 128 + col]);
      const float2 v1 = *reinterpret_cast<const float2*>(&g[(size_t)s1 * 128 + col]);
      const float2 v2 = *reinterpret_cast<const float2*>(&g[(size_t)s2 * 128 + col]);
      const float2 v3 = *reinterpret_cast<const float2*>(&g[(size_t)s3 * 128 + col]);
      acc.x += (v0.x + v1.x) + (v2.x + v3.x);
      acc.y += (v0.y + v1.y) + (v2.y + v3.y);
    }
    for (; e < end; ++e) {
      const int s = csr_src[e];
      const float2 v = *reinterpret_cast<const float2*>(&g[(size_t)s * 128 + col]);
      acc.x += v.x;
      acc.y += v.y;
    }
    const float2 b = *reinterpret_cast<const float2*>(&bias[col]);
    float rx = dd * acc.x + b.x;
    float ry = dd * acc.y + b.y;
    if (RELU) {
      rx = fmaxf(rx, 0.f);
      ry = fmaxf(ry, 0.f);
    }
    *reinterpret_cast<float2*>(&hout[(size_t)wid * 128 + col]) = make_float2(rx, ry);
  } else {  // C == 64
    float acc = g[(size_t)wid * 64 + lane];
    int e = beg;
    for (; e + 4 <= end; e += 4) {
      const int s0 = csr_src[e + 0];
      const int s1 = csr_src[e + 1];
      const int s2 = csr_src[e + 2];
      const int s3 = csr_src[e + 3];
      acc += (g[(size_t)s0 * 64 + lane] + g[(size_t)s1 * 64 + lane]) +
             (g[(size_t)s2 * 64 + lane] + g[(size_t)s3 * 64 + lane]);
    }
    for (; e < end; ++e) acc += g[(size_t)csr_src[e] * 64 + lane];
    hout[(size_t)wid * 64 + lane] = dd * acc + bias[lane];
  }
}

// ---------------------------------------------------------------------------
__global__ __launch_bounds__(256) void decode_k(const int* __restrict__ pos,
                                                const int* __restrict__ neg,
                                                const float* __restrict__ z,
                                                float* __restrict__ out, int EP) {
  const long long t = (long long)blockIdx.x * 256 + threadIdx.x;
  const long long e = t >> 4;
  const int lane = (int)(t & 15);
  if (e >= 2LL * EP) return;
  int u, v;
  if (e < EP) {
    u = pos[e];
    v = pos[EP + e];
  } else {
    u = neg[e - EP];
    v = neg[EP + (e - EP)];
  }
  const float4 a = *reinterpret_cast<const float4*>(&z[(size_t)u * 64 + lane * 4]);
  const float4 b = *reinterpret_cast<const float4*>(&z[(size_t)v * 64 + lane * 4]);
  float p = a.x * b.x + a.y * b.y + a.z * b.z + a.w * b.w;
#pragma unroll
  for (int off = 8; off > 0; off >>= 1) p += __shfl_down(p, off, 16);
  if (lane == 0) out[e] = p;
}

// ---------------------------------------------------------------------------

extern "C" void kernel_launch(void* const* d_in, const int* in_sizes, int n_in,
                              void* d_out, int out_size, void* d_ws, size_t ws_size,
                              hipStream_t stream) {
  const float* x = (const float*)d_in[0];
  const int* ei = (const int*)d_in[1];
  const int* pos = (const int*)d_in[2];
  const int* neg = (const int*)d_in[3];
  const float* W1 = (const float*)d_in[4];
  const float* b1 = (const float*)d_in[5];
  const float* W2 = (const float*)d_in[6];
  const float* b2 = (const float*)d_in[7];
  float* out = (float*)d_out;

  const int H = in_sizes[5];        // 128
  const int IN = in_sizes[4] / H;   // 256
  const int OUT = in_sizes[7];      // 64
  const int N = in_sizes[0] / IN;   // 100000
  const int E = in_sizes[1] / 2;    // 1600000
  const int EP = in_sizes[2] / 2;   // 500000

  char* ws = (char*)d_ws;
  size_t off = 0;
  auto carve = [&](size_t bytes) -> char* {
    char* p = ws + off;
    off += (bytes + 255) & ~(size_t)255;
    return p;
  };
  const int NB = (N + SCAN_CH - 1) / SCAN_CH;
  const int NBUK = (N + BUK_NODES - 1) >> BUK_SHIFT;  // 782

  int* degi = (int*)carve((size_t)N * 4);
  float* dinvb = (float*)carve((size_t)N * 4);
  int* rowptr = (int*)carve((size_t)(N + 1) * 4);
  int* bsums = (int*)carve((size_t)NB * 4);
  int* bhist = (int*)carve((size_t)NBUK * 4);
  int* bbase = (int*)carve((size_t)(NBUK + 1) * 4);
  int* bcur = (int*)carve((size_t)NBUK * 4);
  int2* ebuf = (int2*)carve((size_t)E * 8);
  int* csr = (int*)carve((size_t)E * 4);
  float* bufA = (float*)carve((size_t)N * H * 4);
  float* bufB = (float*)carve((size_t)N * H * 4);
  (void)ws_size;

  const int* srcp = ei;
  const int* dstp = ei + E;

  // --- CSR build via bucketing ---
  hipMemsetAsync(bhist, 0, (size_t)NBUK * 4, stream);
  b_hist_k<<<512, 256, 0, stream>>>(dstp, E, NBUK, bhist);
  b_scan_k<<<1, 256, 0, stream>>>(bhist, NBUK, bbase, bcur);
  b_scatter_k<<<(E + 8191) / 8192, 256, 0, stream>>>(srcp, dstp, E, NBUK, bcur, ebuf);
  b_deg_k<<<NBUK, 128, 0, stream>>>(ebuf, bbase, N, degi, dinvb);
  block_sum_k<<<NB, 256, 0, stream>>>(degi, N, bsums);
  scan_sums_k<<<1, 256, 0, stream>>>(bsums, NB, N, rowptr);
  scan_fill_k<<<NB, 256, 0, stream>>>(degi, N, bsums, rowptr);
  b_fill_k<<<NBUK, 128, 0, stream>>>(ebuf, bbase, rowptr, N, csr);

  // --- encode ---
  gemm_tiled<128, 128, 16, 8, 8>
      <<<(N + 127) / 128, 256, 0, stream>>>(x, W1, bufA, dinvb, N, IN, H);
  agg_k<128, true><<<(N + 3) / 4, 256, 0, stream>>>(bufA, rowptr, csr, dinvb, b1,
                                                    bufB, N);
  gemm_tiled<128, 64, 16, 8, 4>
      <<<(N + 127) / 128, 256, 0, stream>>>(bufB, W2, bufA, dinvb, N, H, OUT);
  agg_k<64, false><<<(N + 3) / 4, 256, 0, stream>>>(bufA, rowptr, csr, dinvb, b2,
                                                    bufB, N);
  // --- decode ---
  const long long threads = 2LL * EP * 16;
  decode_k<<<(int)((threads + 255) / 256), 256, 0, stream>>>(pos, neg, bufB, out, EP);
}

// Round 5
// 473.407 us; speedup vs baseline: 1.9456x; 1.0319x over previous
//
#include <hip/hip_runtime.h>

// ---------------------------------------------------------------------------
// EdgeNet: 2-layer GCN encode + dot-product edge decode, all fp32.
// R5: GEMM restructured for occupancy + conflict-free LDS reads:
//     BM=64 (grid 1563 = 6 blocks/CU), BK=32, micro-tile 8x4 so each wave's
//     Bs b128 read covers the whole 512B row (2-way = free), As transposed
//     [BK][BM+4] so ra = 2x float4 LDS loads (staging exactly 2-way = free).
// ---------------------------------------------------------------------------

#define SCAN_CH 512
#define BUK_SHIFT 7
#define BUK_NODES 128  // nodes per bucket

// --- edge bucketing -------------------------------------------------------
__global__ __launch_bounds__(256) void b_hist_k(const int* __restrict__ dst, int E,
                                                int nbuk, int* __restrict__ bhist) {
  __shared__ int h[1024];
  for (int i = threadIdx.x; i < nbuk; i += 256) h[i] = 0;
  __syncthreads();
  for (int i = blockIdx.x * 256 + threadIdx.x; i < E; i += gridDim.x * 256)
    atomicAdd(&h[dst[i] >> BUK_SHIFT], 1);
  __syncthreads();
  for (int i = threadIdx.x; i < nbuk; i += 256) {
    int c = h[i];
    if (c) atomicAdd(&bhist[i], c);
  }
}

__global__ __launch_bounds__(256) void b_scan_k(const int* __restrict__ bhist,
                                                int nbuk, int* __restrict__ bbase,
                                                int* __restrict__ bcur) {
  __shared__ int arr[256];
  const int t = threadIdx.x;
  const int per = (nbuk + 255) / 256;
  const int start = t * per;
  const int end = min(start + per, nbuk);
  int s = 0;
  for (int i = start; i < end; ++i) s += bhist[i];
  arr[t] = s;
  __syncthreads();
  for (int off = 1; off < 256; off <<= 1) {
    int v = (t >= off) ? arr[t - off] : 0;
    __syncthreads();
    arr[t] += v;
    __syncthreads();
  }
  int run = arr[t] - s;
  for (int i = start; i < end; ++i) {
    bbase[i] = run;
    bcur[i] = run;
    run += bhist[i];
  }
  if (t == 255) bbase[nbuk] = arr[255];
}

// chunk of 8192 edges per block; LDS hist -> reserve -> scatter int2 pairs
__global__ __launch_bounds__(256) void b_scatter_k(const int* __restrict__ src,
                                                   const int* __restrict__ dst, int E,
                                                   int nbuk, int* __restrict__ bcur,
                                                   int2* __restrict__ ebuf) {
  __shared__ int lh[1024];
  __shared__ int lc[1024];
  const int base = blockIdx.x * 8192;
  if (base >= E) return;
  const int end = min(base + 8192, E);
  for (int i = threadIdx.x; i < nbuk; i += 256) lh[i] = 0;
  __syncthreads();
  for (int i = base + threadIdx.x; i < end; i += 256)
    atomicAdd(&lh[dst[i] >> BUK_SHIFT], 1);
  __syncthreads();
  for (int i = threadIdx.x; i < nbuk; i += 256) {
    int c = lh[i];
    lc[i] = c ? atomicAdd(&bcur[i], c) : 0;
  }
  __syncthreads();
  for (int i = base + threadIdx.x; i < end; i += 256) {
    int d = dst[i];
    int pos = atomicAdd(&lc[d >> BUK_SHIFT], 1);
    ebuf[pos] = make_int2(src[i], d);
  }
}

// one block per bucket: degree count in LDS, write deg + dinv coalesced
__global__ __launch_bounds__(128) void b_deg_k(const int2* __restrict__ ebuf,
                                               const int* __restrict__ bbase, int n,
                                               int* __restrict__ deg,
                                               float* __restrict__ dinv) {
  __shared__ int cnt[BUK_NODES];
  const int b = blockIdx.x;
  cnt[threadIdx.x] = 0;
  __syncthreads();
  const int beg = bbase[b], end = bbase[b + 1];
  for (int i = beg + threadIdx.x; i < end; i += 128)
    atomicAdd(&cnt[ebuf[i].y & (BUK_NODES - 1)], 1);
  __syncthreads();
  const int node = (b << BUK_SHIFT) + threadIdx.x;
  if (node < n) {
    int c = cnt[threadIdx.x];
    deg[node] = c;
    dinv[node] = rsqrtf((float)(c + 1));  // +1 self-loop
  }
}

// one block per bucket: CSR fill with LDS cursors (no global atomics)
__global__ __launch_bounds__(128) void b_fill_k(const int2* __restrict__ ebuf,
                                                const int* __restrict__ bbase,
                                                const int* __restrict__ rowptr, int n,
                                                int* __restrict__ csr) {
  __shared__ int cur[BUK_NODES];
  const int b = blockIdx.x;
  const int node = (b << BUK_SHIFT) + threadIdx.x;
  cur[threadIdx.x] = (node < n) ? rowptr[node] : 0;
  __syncthreads();
  const int beg = bbase[b], end = bbase[b + 1];
  for (int i = beg + threadIdx.x; i < end; i += 128) {
    int2 e = ebuf[i];
    int pos = atomicAdd(&cur[e.y & (BUK_NODES - 1)], 1);
    csr[pos] = e.x;
  }
}

// --- 3-phase scan over node degrees -> rowptr -----------------------------
__global__ __launch_bounds__(256) void block_sum_k(const int* __restrict__ cnt, int n,
                                                   int* __restrict__ sums) {
  __shared__ int tsum[256];
  const int b = blockIdx.x, t = threadIdx.x;
  const int base = b * SCAN_CH + t * 2;
  int s = 0;
  if (base < n) s += cnt[base];
  if (base + 1 < n) s += cnt[base + 1];
  tsum[t] = s;
  __syncthreads();
  for (int off = 128; off > 0; off >>= 1) {
    if (t < off) tsum[t] += tsum[t + off];
    __syncthreads();
  }
  if (t == 0) sums[b] = tsum[0];
}

__global__ __launch_bounds__(256) void scan_sums_k(int* __restrict__ sums, int nb,
                                                   int n, int* __restrict__ rowptr) {
  __shared__ int arr[256];
  const int t = threadIdx.x;
  const int per = (nb + 255) / 256;
  const int start = t * per;
  const int end = min(start + per, nb);
  int s = 0;
  for (int i = start; i < end; ++i) s += sums[i];
  arr[t] = s;
  __syncthreads();
  for (int off = 1; off < 256; off <<= 1) {
    int v = (t >= off) ? arr[t - off] : 0;
    __syncthreads();
    arr[t] += v;
    __syncthreads();
  }
  int run = arr[t] - s;
  for (int i = start; i < end; ++i) {
    int c = sums[i];
    sums[i] = run;
    run += c;
  }
  if (t == 255) rowptr[n] = arr[255];
}

__global__ __launch_bounds__(256) void scan_fill_k(const int* __restrict__ cnt, int n,
                                                   const int* __restrict__ blockoff,
                                                   int* __restrict__ rowptr) {
  __shared__ int tsum[256];
  const int b = blockIdx.x, t = threadIdx.x;
  const int base = b * SCAN_CH + t * 2;
  const int c0 = (base < n) ? cnt[base] : 0;
  const int c1 = (base + 1 < n) ? cnt[base + 1] : 0;
  const int s = c0 + c1;
  tsum[t] = s;
  __syncthreads();
  for (int off = 1; off < 256; off <<= 1) {
    int v = (t >= off) ? tsum[t - off] : 0;
    __syncthreads();
    tsum[t] += v;
    __syncthreads();
  }
  const int pre = blockoff[b] + tsum[t] - s;
  if (base < n) rowptr[base] = pre;
  if (base + 1 < n) rowptr[base + 1] = pre + c0;
}

// ---------------------------------------------------------------------------
// fp32 tiled GEMM, C[M,N] = rowscale[m] * (A[M,K] @ B[K,N]).  BN == N.
// As[BK][BM+4] transposed (staging stores exactly 2-way = free; ra loads are
// contiguous float4). Bs[BK][BN+4]; with BN/TN==32, a wave's rb b128 reads
// span the full row -> worst 2-way aliasing. TM,TN multiples of 4.
// ---------------------------------------------------------------------------
template <int BM, int BN, int BK, int TM, int TN>
__global__ __launch_bounds__(256) void gemm_tiled(const float* __restrict__ A,
                                                  const float* __restrict__ B,
                                                  float* __restrict__ C,
                                                  const float* __restrict__ rowscale,
                                                  int M, int K, int N) {
  __shared__ float As[BK][BM + 4];
  __shared__ float Bs[BK][BN + 4];
  const int tid = threadIdx.x;
  const int tx = tid % (BN / TN);
  const int ty = tid / (BN / TN);
  const int rowBase = blockIdx.x * BM;

  float acc[TM][TN];
#pragma unroll
  for (int i = 0; i < TM; ++i)
#pragma unroll
    for (int j = 0; j < TN; ++j) acc[i][j] = 0.f;

  for (int k0 = 0; k0 < K; k0 += BK) {
#pragma unroll
    for (int l = 0; l < BM * BK / (4 * 256); ++l) {
      const int idx = tid + l * 256;
      const int arow = idx / (BK / 4);
      const int acol = (idx % (BK / 4)) * 4;
      const int gr = rowBase + arow;
      float4 v;
      if (gr < M)
        v = *reinterpret_cast<const float4*>(&A[(size_t)gr * K + k0 + acol]);
      else
        v = make_float4(0.f, 0.f, 0.f, 0.f);
      As[acol + 0][arow] = v.x;
      As[acol + 1][arow] = v.y;
      As[acol + 2][arow] = v.z;
      As[acol + 3][arow] = v.w;
    }
#pragma unroll
    for (int l = 0; l < BK * BN / (4 * 256); ++l) {
      const int idx = tid + l * 256;
      const int brow = idx / (BN / 4);
      const int bcol4 = (idx % (BN / 4)) * 4;
      *reinterpret_cast<float4*>(&Bs[brow][bcol4]) =
          *reinterpret_cast<const float4*>(&B[(size_t)(k0 + brow) * N + bcol4]);
    }
    __syncthreads();
#pragma unroll
    for (int kk = 0; kk < BK; ++kk) {
      float ra[TM], rb[TN];
#pragma unroll
      for (int i = 0; i < TM; i += 4)
        *reinterpret_cast<float4*>(&ra[i]) =
            *reinterpret_cast<const float4*>(&As[kk][ty * TM + i]);
#pragma unroll
      for (int j = 0; j < TN; j += 4)
        *reinterpret_cast<float4*>(&rb[j]) =
            *reinterpret_cast<const float4*>(&Bs[kk][tx * TN + j]);
#pragma unroll
      for (int i = 0; i < TM; ++i)
#pragma unroll
        for (int j = 0; j < TN; ++j) acc[i][j] += ra[i] * rb[j];
    }
    __syncthreads();
  }
#pragma unroll
  for (int i = 0; i < TM; ++i) {
    const int gr = rowBase + ty * TM + i;
    if (gr < M) {
      const float s = rowscale ? rowscale[gr] : 1.f;
#pragma unroll
      for (int j = 0; j < TN; j += 4) {
        float4 v = {acc[i][j] * s, acc[i][j + 1] * s, acc[i][j + 2] * s,
                    acc[i][j + 3] * s};
        *reinterpret_cast<float4*>(&C[(size_t)gr * N + tx * TN + j]) = v;
      }
    }
  }
}

// ---------------------------------------------------------------------------
// Aggregation over pre-scaled features g = dinv[i]*h[i]:
//   out[d] = RELU?( dinv[d] * (sum_{s in N(d)} g[s] + g[d]) + bias )
// ---------------------------------------------------------------------------
template <int C, bool RELU>
__global__ __launch_bounds__(256) void agg_k(const float* __restrict__ g,
                                             const int* __restrict__ rowptr,
                                             const int* __restrict__ csr_src,
                                             const float* __restrict__ dinv,
                                             const float* __restrict__ bias,
                                             float* __restrict__ hout, int n) {
  const int wid = (blockIdx.x * blockDim.x + threadIdx.x) >> 6;
  const int lane = threadIdx.x & 63;
  if (wid >= n) return;
  const float dd = dinv[wid];
  const int beg = rowptr[wid];
  const int end = rowptr[wid + 1];
  if (C == 128) {
    const size_t col = (size_t)lane * 2;
    float2 acc = *reinterpret_cast<const float2*>(&g[(size_t)wid * 128 + col]);
    int e = beg;
    for (; e + 4 <= end; e += 4) {
      const int s0 = csr_src[e + 0];
      const int s1 = csr_src[e + 1];
      const int s2 = csr_src[e + 2];
      const int s3 = csr_src[e + 3];
      const float2 v0 = *reinterpret_cast<const float2*>(&g[(size_t)s0 * 128 + col]);
      const float2 v1 = *reinterpret_cast<const float2*>(&g[(size_t)s1 * 128 + col]);
      const float2 v2 = *reinterpret_cast<const float2*>(&g[(size_t)s2 * 128 + col]);
      const float2 v3 = *reinterpret_cast<const float2*>(&g[(size_t)s3 * 128 + col]);
      acc.x += (v0.x + v1.x) + (v2.x + v3.x);
      acc.y += (v0.y + v1.y) + (v2.y + v3.y);
    }
    for (; e < end; ++e) {
      const int s = csr_src[e];
      const float2 v = *reinterpret_cast<const float2*>(&g[(size_t)s * 128 + col]);
      acc.x += v.x;
      acc.y += v.y;
    }
    const float2 b = *reinterpret_cast<const float2*>(&bias[col]);
    float rx = dd * acc.x + b.x;
    float ry = dd * acc.y + b.y;
    if (RELU) {
      rx = fmaxf(rx, 0.f);
      ry = fmaxf(ry, 0.f);
    }
    *reinterpret_cast<float2*>(&hout[(size_t)wid * 128 + col]) = make_float2(rx, ry);
  } else {  // C == 64
    float acc = g[(size_t)wid * 64 + lane];
    int e = beg;
    for (; e + 4 <= end; e += 4) {
      const int s0 = csr_src[e + 0];
      const int s1 = csr_src[e + 1];
      const int s2 = csr_src[e + 2];
      const int s3 = csr_src[e + 3];
      acc += (g[(size_t)s0 * 64 + lane] + g[(size_t)s1 * 64 + lane]) +
             (g[(size_t)s2 * 64 + lane] + g[(size_t)s3 * 64 + lane]);
    }
    for (; e < end; ++e) acc += g[(size_t)csr_src[e] * 64 + lane];
    hout[(size_t)wid * 64 + lane] = dd * acc + bias[lane];
  }
}

// ---------------------------------------------------------------------------
__global__ __launch_bounds__(256) void decode_k(const int* __restrict__ pos,
                                                const int* __restrict__ neg,
                                                const float* __restrict__ z,
                                                float* __restrict__ out, int EP) {
  const long long t = (long long)blockIdx.x * 256 + threadIdx.x;
  const long long e = t >> 4;
  const int lane = (int)(t & 15);
  if (e >= 2LL * EP) return;
  int u, v;
  if (e < EP) {
    u = pos[e];
    v = pos[EP + e];
  } else {
    u = neg[e - EP];
    v = neg[EP + (e - EP)];
  }
  const float4 a = *reinterpret_cast<const float4*>(&z[(size_t)u * 64 + lane * 4]);
  const float4 b = *reinterpret_cast<const float4*>(&z[(size_t)v * 64 + lane * 4]);
  float p = a.x * b.x + a.y * b.y + a.z * b.z + a.w * b.w;
#pragma unroll
  for (int off = 8; off > 0; off >>= 1) p += __shfl_down(p, off, 16);
  if (lane == 0) out[e] = p;
}

// ---------------------------------------------------------------------------

extern "C" void kernel_launch(void* const* d_in, const int* in_sizes, int n_in,
                              void* d_out, int out_size, void* d_ws, size_t ws_size,
                              hipStream_t stream) {
  const float* x = (const float*)d_in[0];
  const int* ei = (const int*)d_in[1];
  const int* pos = (const int*)d_in[2];
  const int* neg = (const int*)d_in[3];
  const float* W1 = (const float*)d_in[4];
  const float* b1 = (const float*)d_in[5];
  const float* W2 = (const float*)d_in[6];
  const float* b2 = (const float*)d_in[7];
  float* out = (float*)d_out;

  const int H = in_sizes[5];        // 128
  const int IN = in_sizes[4] / H;   // 256
  const int OUT = in_sizes[7];      // 64
  const int N = in_sizes[0] / IN;   // 100000
  const int E = in_sizes[1] / 2;    // 1600000
  const int EP = in_sizes[2] / 2;   // 500000

  char* ws = (char*)d_ws;
  size_t off = 0;
  auto carve = [&](size_t bytes) -> char* {
    char* p = ws + off;
    off += (bytes + 255) & ~(size_t)255;
    return p;
  };
  const int NB = (N + SCAN_CH - 1) / SCAN_CH;
  const int NBUK = (N + BUK_NODES - 1) >> BUK_SHIFT;  // 782

  int* degi = (int*)carve((size_t)N * 4);
  float* dinvb = (float*)carve((size_t)N * 4);
  int* rowptr = (int*)carve((size_t)(N + 1) * 4);
  int* bsums = (int*)carve((size_t)NB * 4);
  int* bhist = (int*)carve((size_t)NBUK * 4);
  int* bbase = (int*)carve((size_t)(NBUK + 1) * 4);
  int* bcur = (int*)carve((size_t)NBUK * 4);
  int2* ebuf = (int2*)carve((size_t)E * 8);
  int* csr = (int*)carve((size_t)E * 4);
  float* bufA = (float*)carve((size_t)N * H * 4);
  float* bufB = (float*)carve((size_t)N * H * 4);
  (void)ws_size;

  const int* srcp = ei;
  const int* dstp = ei + E;

  // --- CSR build via bucketing ---
  hipMemsetAsync(bhist, 0, (size_t)NBUK * 4, stream);
  b_hist_k<<<512, 256, 0, stream>>>(dstp, E, NBUK, bhist);
  b_scan_k<<<1, 256, 0, stream>>>(bhist, NBUK, bbase, bcur);
  b_scatter_k<<<(E + 8191) / 8192, 256, 0, stream>>>(srcp, dstp, E, NBUK, bcur, ebuf);
  b_deg_k<<<NBUK, 128, 0, stream>>>(ebuf, bbase, N, degi, dinvb);
  block_sum_k<<<NB, 256, 0, stream>>>(degi, N, bsums);
  scan_sums_k<<<1, 256, 0, stream>>>(bsums, NB, N, rowptr);
  scan_fill_k<<<NB, 256, 0, stream>>>(degi, N, bsums, rowptr);
  b_fill_k<<<NBUK, 128, 0, stream>>>(ebuf, bbase, rowptr, N, csr);

  // --- encode ---
  gemm_tiled<64, 128, 32, 8, 4>
      <<<(N + 63) / 64, 256, 0, stream>>>(x, W1, bufA, dinvb, N, IN, H);
  agg_k<128, true><<<(N + 3) / 4, 256, 0, stream>>>(bufA, rowptr, csr, dinvb, b1,
                                                    bufB, N);
  gemm_tiled<64, 64, 32, 4, 4>
      <<<(N + 63) / 64, 256, 0, stream>>>(bufB, W2, bufA, dinvb, N, H, OUT);
  agg_k<64, false><<<(N + 3) / 4, 256, 0, stream>>>(bufA, rowptr, csr, dinvb, b2,
                                                    bufB, N);
  // --- decode ---
  const long long threads = 2LL * EP * 16;
  decode_k<<<(int)((threads + 255) / 256), 256, 0, stream>>>(pos, neg, bufB, out, EP);
}